// Round 3
// baseline (399.808 us; speedup 1.0000x reference)
//
#include <hip/hip_runtime.h>
#include <cstdint>
#include <cstddef>

typedef _Float16 f16;
typedef f16 f16x8 __attribute__((ext_vector_type(8)));
typedef float f32x4 __attribute__((ext_vector_type(4)));

#define B_ROWS 65536
#define NT_BRANCH 1030   // worst-case branch tiles: 1024 + 6 bins' padding
#define NT_SPEED 1024    // 65536/64

// ---------------- ws layout (all offsets 256B-aligned) ----------------
constexpr size_t OFF_SF16   = 0;
constexpr size_t SZ_SF16    = (size_t)B_ROWS * 128 * 2;        // 16,777,216
constexpr size_t OFF_SIW2T  = OFF_SF16 + SZ_SF16;
constexpr size_t SZ_SIW2T   = (size_t)128 * 256 * 2;
constexpr size_t OFF_BW1T   = OFF_SIW2T + SZ_SIW2T;
constexpr size_t SZ_BW1T    = (size_t)6 * 256 * 640 * 2;
constexpr size_t OFF_BW2T   = OFF_BW1T + SZ_BW1T;
constexpr size_t SZ_BW2T    = (size_t)6 * 256 * 256 * 2;
constexpr size_t OFF_SOW1T  = OFF_BW2T + SZ_BW2T;
constexpr size_t SZ_SOW1T   = (size_t)256 * 640 * 2;
constexpr size_t OFF_SOW2T  = OFF_SOW1T + SZ_SOW1T;
constexpr size_t SZ_SOW2T   = (size_t)256 * 256 * 2;
constexpr size_t OFF_BW3T16 = OFF_SOW2T + SZ_SOW2T;
constexpr size_t SZ_BW3T16  = (size_t)6 * 16 * 256 * 2;        // zero-padded cols 3..15
constexpr size_t OFF_SOW3T16= OFF_BW3T16 + SZ_BW3T16;
constexpr size_t SZ_SOW3T16 = (size_t)16 * 256 * 2;
constexpr size_t OFF_COUNTS = OFF_SOW3T16 + SZ_SOW3T16;
constexpr size_t OFF_CURSORS= OFF_COUNTS + 256;
constexpr size_t OFF_BINBASE= OFF_CURSORS + 256;
constexpr size_t OFF_TILECMD= OFF_BINBASE + 256;
constexpr size_t OFF_PERM   = OFF_TILECMD + 4352;
constexpr size_t WS_NEEDED  = OFF_PERM + (size_t)NT_BRANCH * 64 * 4;  // ~20.5 MB

#define MFMA16(a, b, c) __builtin_amdgcn_mfma_f32_16x16x32_f16(a, b, c, 0, 0, 0)
// Barrier without the vmcnt(0) drain: LDS ordering only needs lgkmcnt; global
// prefetch loads stay in flight across it (their register deps carry counted
// vmcnt waits at first use).
#define BARSYNC() asm volatile("s_waitcnt lgkmcnt(0)\n\ts_barrier" ::: "memory")

// ---------------- prep: transpose-cast weights + W3T16 + init sort scratch ----------------
__global__ void prep_kernel(const float* __restrict__ siW2,
                            const float* __restrict__ bW1,
                            const float* __restrict__ bW2,
                            const float* __restrict__ soW1,
                            const float* __restrict__ soW2,
                            const float* __restrict__ bW3,
                            const float* __restrict__ soW3,
                            f16* __restrict__ siW2T, f16* __restrict__ bW1T,
                            f16* __restrict__ bW2T, f16* __restrict__ soW1T,
                            f16* __restrict__ soW2T,
                            f16* __restrict__ bW3T16, f16* __restrict__ soW3T16,
                            int* __restrict__ counts, int* __restrict__ cursors,
                            int* __restrict__ perm)
{
    const int bx = blockIdx.x;
    const int tx = threadIdx.x, ty = threadIdx.y;
    const int tid = ty * 32 + tx;
    if (bx >= 1601) {                       // perm init + counter zero
        const int ib = bx - 1601;
        const int idx = ib * 256 + tid;
        if (idx < NT_BRANCH * 64) perm[idx] = -1;
        if (ib == 0 && tid < 6) { counts[tid] = 0; cursors[tid] = 0; }
        return;
    }
    if (bx == 1600) {                       // W3 -> padded-16-col f16, [n][k] layout
        for (int i = tid; i < 6 * 16 * 256; i += 256) {
            const int c = i >> 12, rem = i & 4095, n = rem >> 8, k = rem & 255;
            bW3T16[i] = (n < 3) ? (f16)bW3[((size_t)c * 256 + k) * 3 + n] : (f16)0;
        }
        for (int i = tid; i < 16 * 256; i += 256) {
            const int n = i >> 8, k = i & 255;
            soW3T16[i] = (n == 0) ? (f16)soW3[k] : (f16)0;
        }
        return;
    }
    const float* in; f16* out; int R, C, lb;
    if (bx < 960)       { int m = bx / 160;        lb = bx - m * 160;       in = bW1 + (size_t)m * 640 * 256; out = bW1T + (size_t)m * 640 * 256; R = 640; C = 256; }
    else if (bx < 1344) { int m = (bx - 960) / 64; lb = (bx - 960) - m * 64; in = bW2 + (size_t)m * 256 * 256; out = bW2T + (size_t)m * 256 * 256; R = 256; C = 256; }
    else if (bx < 1504) { lb = bx - 1344; in = soW1; out = soW1T; R = 640; C = 256; }
    else if (bx < 1568) { lb = bx - 1504; in = soW2; out = soW2T; R = 256; C = 256; }
    else                { lb = bx - 1568; in = siW2; out = siW2T; R = 256; C = 128; }
    const int txt = C >> 5;
    const int c0 = (lb % txt) << 5;
    const int r0 = (lb / txt) << 5;
    __shared__ float tile[32][33];
    #pragma unroll
    for (int i = 0; i < 4; ++i)
        tile[tx][ty + 8 * i] = in[(size_t)(r0 + ty + 8 * i) * C + c0 + tx];
    __syncthreads();
    #pragma unroll
    for (int i = 0; i < 4; ++i)
        out[(size_t)(c0 + ty + 8 * i) * R + r0 + tx] = (f16)tile[ty + 8 * i][tx];
}

// ---------------- speed_in MLP (+ fused histogram): sF16 = relu(speed*W1+b1)@W2+b2 ----------------
__global__ __launch_bounds__(256) void speedin_kernel(
    const float* __restrict__ speed,
    const float* __restrict__ siW1, const float* __restrict__ sib1,
    const f16* __restrict__ siW2T, const float* __restrict__ sib2,
    const int* __restrict__ cmd,
    f16* __restrict__ sF16, int* __restrict__ counts)
{
    __shared__ f16 H[64 * 264];
    __shared__ float spd[64];
    __shared__ int h[6];
    const int tid = threadIdx.x;
    const int rb = blockIdx.x * 64;
    if (tid < 6) h[tid] = 0;
    __syncthreads();
    if (tid < 64) {
        spd[tid] = speed[rb + tid];
        atomicAdd(&h[cmd[rb + tid] - 1], 1);
    }
    __syncthreads();
    if (tid < 6 && h[tid] > 0) atomicAdd(&counts[tid], h[tid]);
    {
        const float w1 = siW1[tid], b1v = sib1[tid];
        #pragma unroll 4
        for (int r = 0; r < 64; ++r) {
            float hv = spd[r] * w1 + b1v;
            H[r * 264 + tid] = (f16)(hv > 0.f ? hv : 0.f);
        }
    }
    __syncthreads();
    const int w = tid >> 6, lane = tid & 63, lq = lane >> 4, l16 = lane & 15;
    const int nb = w * 32;
    f32x4 acc[4][2];
    #pragma unroll
    for (int mt = 0; mt < 4; ++mt)
        #pragma unroll
        for (int nt = 0; nt < 2; ++nt)
            acc[mt][nt] = (f32x4){0.f, 0.f, 0.f, 0.f};
    for (int ks = 0; ks < 8; ++ks) {
        const int koff = ks * 32 + lq * 8;
        f16x8 af[4], bf[2];
        #pragma unroll
        for (int mt = 0; mt < 4; ++mt)
            af[mt] = *(const f16x8*)(&H[(mt * 16 + l16) * 264 + koff]);
        #pragma unroll
        for (int nt = 0; nt < 2; ++nt)
            bf[nt] = *(const f16x8*)(siW2T + (size_t)(nb + nt * 16 + l16) * 256 + koff);
        #pragma unroll
        for (int mt = 0; mt < 4; ++mt)
            #pragma unroll
            for (int nt = 0; nt < 2; ++nt)
                acc[mt][nt] = MFMA16(af[mt], bf[nt], acc[mt][nt]);
    }
    #pragma unroll
    for (int mt = 0; mt < 4; ++mt)
        #pragma unroll
        for (int nt = 0; nt < 2; ++nt) {
            const int n = nb + nt * 16 + l16;
            const float bv = sib2[n];
            #pragma unroll
            for (int r2 = 0; r2 < 4; ++r2) {
                const int m = mt * 16 + lq * 4 + r2;
                sF16[(size_t)(rb + m) * 128 + n] = (f16)(acc[mt][nt][r2] + bv);
            }
        }
}

// ---------------- plan: bin bases + tile->command map ----------------
__global__ void plan_kernel(const int* __restrict__ counts,
                            int* __restrict__ binBase, int* __restrict__ tile_cmd) {
    __shared__ int tbase[7];
    if (threadIdx.x == 0) {
        int base = 0, tb = 0;
        for (int c = 0; c < 6; ++c) {
            binBase[c] = base;
            tbase[c] = tb;
            const int nt = (counts[c] + 63) >> 6;
            tb += nt;
            base += nt << 6;
        }
        tbase[6] = tb;
    }
    __syncthreads();
    for (int t = threadIdx.x; t < NT_BRANCH; t += 256) {
        int c = -1;
        #pragma unroll
        for (int j = 0; j < 6; ++j)
            if (t >= tbase[j] && t < tbase[j + 1]) c = j;
        tile_cmd[t] = c;
    }
}

__global__ void place_kernel(const int* __restrict__ cmd,
                             const int* __restrict__ binBase,
                             int* __restrict__ cursors, int* __restrict__ perm) {
    __shared__ int lcnt[6], lbase[6];
    const int tid = threadIdx.x;
    if (tid < 6) lcnt[tid] = 0;
    __syncthreads();
    const int i = blockIdx.x * 256 + tid;
    const int c = cmd[i] - 1;
    const int myr = atomicAdd(&lcnt[c], 1);
    __syncthreads();
    if (tid < 6) lbase[tid] = atomicAdd(&cursors[tid], lcnt[tid]);
    __syncthreads();
    perm[binBase[c] + lbase[c] + myr] = i;
}

// One GEMM1 K-chunk (64 cols): LDS A-frags + register B, with next-chunk B
// prefetch (L2-resident weights). LCOL = col base within the staged half;
// NGCOL = global col base of the next chunk's B.
template<bool PREF>
__device__ __forceinline__ void kc_iter(const f16* __restrict__ smem,
                                        const f16* __restrict__ brow0,
                                        const f16* __restrict__ brow1,
                                        f16x8 (&Bb)[2][2], f32x4 (&acc)[4][2],
                                        int LCOL, int NGCOL, int l16, int lq)
{
    f16x8 Bn[2][2];
    if (PREF) {
        #pragma unroll
        for (int ks = 0; ks < 2; ++ks) {
            Bn[ks][0] = *(const f16x8*)(brow0 + NGCOL + ks * 32 + lq * 8);
            Bn[ks][1] = *(const f16x8*)(brow1 + NGCOL + ks * 32 + lq * 8);
        }
    }
    f16x8 a_[2][4];
    #pragma unroll
    for (int ks = 0; ks < 2; ++ks)
        #pragma unroll
        for (int mt = 0; mt < 4; ++mt)
            a_[ks][mt] = *(const f16x8*)(smem + (mt * 16 + l16) * 328 + LCOL + ks * 32 + lq * 8);
    #pragma unroll
    for (int ks = 0; ks < 2; ++ks)
        #pragma unroll
        for (int mt = 0; mt < 4; ++mt)
            #pragma unroll
            for (int nt = 0; nt < 2; ++nt)
                acc[mt][nt] = MFMA16(a_[ks][mt], Bb[ks][nt], acc[mt][nt]);
    if (PREF) {
        #pragma unroll
        for (int ks = 0; ks < 2; ++ks)
            #pragma unroll
            for (int nt = 0; nt < 2; ++nt)
                Bb[ks][nt] = Bn[ks][nt];
    }
}

// ---------------- heads: fused 3-layer MLP, half-tile burst-staged A ----------------
// 512 threads = 8 waves; wave-tile 64x32 (acc 4x2); M=64 rows per block.
// A staged in two bursts of 64x320 f16 into LDS [64][328] (41,984B); each
// burst issues all 10 loads at once (latency paid once, not per chunk), then
// 5 K-chunks run pure-LDS + L2-B with NO global-dependent barriers inside.
// h buffers alias the A region. 8 barriers/block total (was 13).
__global__ __launch_bounds__(512, 4) void heads_kernel(
    const float* __restrict__ emb,        // [B,512] fp32
    const f16* __restrict__ sF16,         // [B,128]
    const int* __restrict__ perm, const int* __restrict__ tile_cmd,
    const f16* __restrict__ bW1T, const f16* __restrict__ bW2T,
    const f16* __restrict__ bW3T16,
    const float* __restrict__ bb1, const float* __restrict__ bb2,
    const float* __restrict__ bb3,
    const f16* __restrict__ soW1T, const f16* __restrict__ soW2T,
    const f16* __restrict__ soW3T16,
    const float* __restrict__ sob1, const float* __restrict__ sob2,
    const float* __restrict__ sob3,
    float* __restrict__ out)
{
    __shared__ f16 smem[64 * 328];        // A half-tile; h [64][264] aliases base
    __shared__ int rowIdx[64];
    const int bx = blockIdx.x;
    const int tid = threadIdx.x;
    const bool is_speed = (bx >= NT_BRANCH);
    const f16 *W1T, *W2T, *W3T;
    const float *bias1, *bias2, *bias3;
    if (is_speed) {
        const int t = bx - NT_BRANCH;
        if (tid < 64) rowIdx[tid] = t * 64 + tid;
        W1T = soW1T; W2T = soW2T; W3T = soW3T16;
        bias1 = sob1; bias2 = sob2; bias3 = sob3;
    } else {
        const int c = tile_cmd[bx];
        if (c < 0) return;               // block-uniform
        if (tid < 64) rowIdx[tid] = perm[bx * 64 + tid];
        W1T = bW1T + (size_t)c * 256 * 640;
        W2T = bW2T + (size_t)c * 256 * 256;
        W3T = bW3T16 + (size_t)c * 16 * 256;
        bias1 = bb1 + c * 256; bias2 = bb2 + c * 256; bias3 = bb3 + c * 3;
    }
    __syncthreads();

    // staging role: thread covers row r, 8-col group p of each 64-col chunk
    const int r = tid >> 3, p = tid & 7;
    int growS = rowIdx[r]; if (growS < 0) growS = 0;
    const float* srcF = emb + (size_t)growS * 512;
    const f16*   srcH = sF16 + (size_t)growS * 128;
    const int wOff = r * 328 + p * 8;

    const int w = tid >> 6, lane = tid & 63, lq = lane >> 4, l16 = lane & 15;
    const int nb = w * 32;               // wave's N slice of 256
    const f16* brow0 = W1T + (size_t)(nb + l16) * 640;
    const f16* brow1 = W1T + (size_t)(nb + 16 + l16) * 640;

    // kc0 B prefetch first: arrives while A-half0 stages
    f16x8 Bb[2][2];
    #pragma unroll
    for (int ks = 0; ks < 2; ++ks) {
        Bb[ks][0] = *(const f16x8*)(brow0 + ks * 32 + lq * 8);
        Bb[ks][1] = *(const f16x8*)(brow1 + ks * 32 + lq * 8);
    }

    // ---- stage half 0 (cols 0..319, fp32): all 10 loads in flight at once
    float4 s0[5][2];
    #pragma unroll
    for (int c = 0; c < 5; ++c) {
        const float* s = srcF + c * 64 + p * 8;
        s0[c][0] = ((const float4*)s)[0];
        s0[c][1] = ((const float4*)s)[1];
    }
    #pragma unroll
    for (int c = 0; c < 5; ++c) {
        f16x8 v;
        v[0] = (f16)s0[c][0].x; v[1] = (f16)s0[c][0].y;
        v[2] = (f16)s0[c][0].z; v[3] = (f16)s0[c][0].w;
        v[4] = (f16)s0[c][1].x; v[5] = (f16)s0[c][1].y;
        v[6] = (f16)s0[c][1].z; v[7] = (f16)s0[c][1].w;
        *(f16x8*)(smem + wOff + c * 64) = v;
    }

    f32x4 acc[4][2];
    #pragma unroll
    for (int mt = 0; mt < 4; ++mt)
        #pragma unroll
        for (int nt = 0; nt < 2; ++nt)
            acc[mt][nt] = (f32x4){0.f, 0.f, 0.f, 0.f};

    BARSYNC();                            // A half0 visible

    kc_iter<true>(smem, brow0, brow1, Bb, acc,   0,  64, l16, lq);
    kc_iter<true>(smem, brow0, brow1, Bb, acc,  64, 128, l16, lq);
    kc_iter<true>(smem, brow0, brow1, Bb, acc, 128, 192, l16, lq);

    // issue half-1 staging loads here: latency hides under kc3,kc4 + barrier
    float4 s1[3][2];
    f16x8 t1[2];
    #pragma unroll
    for (int c = 0; c < 3; ++c) {
        const float* s = srcF + 320 + c * 64 + p * 8;
        s1[c][0] = ((const float4*)s)[0];
        s1[c][1] = ((const float4*)s)[1];
    }
    t1[0] = *(const f16x8*)(srcH + p * 8);
    t1[1] = *(const f16x8*)(srcH + 64 + p * 8);

    kc_iter<true>(smem, brow0, brow1, Bb, acc, 192, 256, l16, lq);
    kc_iter<true>(smem, brow0, brow1, Bb, acc, 256, 320, l16, lq);  // prefetches kc5 B

    BARSYNC();                            // all half0 A-reads done; safe to overwrite
    #pragma unroll
    for (int c = 0; c < 3; ++c) {
        f16x8 v;
        v[0] = (f16)s1[c][0].x; v[1] = (f16)s1[c][0].y;
        v[2] = (f16)s1[c][0].z; v[3] = (f16)s1[c][0].w;
        v[4] = (f16)s1[c][1].x; v[5] = (f16)s1[c][1].y;
        v[6] = (f16)s1[c][1].z; v[7] = (f16)s1[c][1].w;
        *(f16x8*)(smem + wOff + c * 64) = v;
    }
    *(f16x8*)(smem + wOff + 192) = t1[0];
    *(f16x8*)(smem + wOff + 256) = t1[1];
    BARSYNC();                            // A half1 visible

    kc_iter<true >(smem, brow0, brow1, Bb, acc,   0, 384, l16, lq);
    kc_iter<true >(smem, brow0, brow1, Bb, acc,  64, 448, l16, lq);
    kc_iter<true >(smem, brow0, brow1, Bb, acc, 128, 512, l16, lq);
    kc_iter<true >(smem, brow0, brow1, Bb, acc, 192, 576, l16, lq);
    kc_iter<false>(smem, brow0, brow1, Bb, acc, 256,   0, l16, lq);

    // prefetch GEMM2 B (ks=0) before the barrier/epilogue
    const f16* brow2[2];
    #pragma unroll
    for (int nt = 0; nt < 2; ++nt)
        brow2[nt] = W2T + (size_t)(nb + nt * 16 + l16) * 256;
    f16x8 Bd[2][2];
    #pragma unroll
    for (int nt = 0; nt < 2; ++nt)
        Bd[0][nt] = *(const f16x8*)(brow2[nt] + lq * 8);

    BARSYNC();                            // all A-reads done; h may overwrite A region

    // h1 = relu(acc + b1) -> smem [64][264]
    #pragma unroll
    for (int mt = 0; mt < 4; ++mt)
        #pragma unroll
        for (int nt = 0; nt < 2; ++nt) {
            const int n = nb + nt * 16 + l16;
            const float bv = bias1[n];
            #pragma unroll
            for (int r2 = 0; r2 < 4; ++r2) {
                const int m = mt * 16 + lq * 4 + r2;
                const float v = acc[mt][nt][r2] + bv;
                smem[m * 264 + n] = (f16)(v > 0.f ? v : 0.f);
            }
            acc[mt][nt] = (f32x4){0.f, 0.f, 0.f, 0.f};
        }
    BARSYNC();

    // ---- GEMM2: K=256, A=h1 (LDS), B dbuf one ks ahead
    #pragma unroll
    for (int ks = 0; ks < 8; ++ks) {
        if (ks < 7) {
            #pragma unroll
            for (int nt = 0; nt < 2; ++nt)
                Bd[(ks + 1) & 1][nt] = *(const f16x8*)(brow2[nt] + (ks + 1) * 32 + lq * 8);
        }
        f16x8 a[4];
        #pragma unroll
        for (int mt = 0; mt < 4; ++mt)
            a[mt] = *(const f16x8*)(&smem[(mt * 16 + l16) * 264 + ks * 32 + lq * 8]);
        #pragma unroll
        for (int mt = 0; mt < 4; ++mt)
            #pragma unroll
            for (int nt = 0; nt < 2; ++nt)
                acc[mt][nt] = MFMA16(a[mt], Bd[ks & 1][nt], acc[mt][nt]);
    }
    BARSYNC();
    // h2 = relu(acc + b2) -> smem
    #pragma unroll
    for (int mt = 0; mt < 4; ++mt)
        #pragma unroll
        for (int nt = 0; nt < 2; ++nt) {
            const int n = nb + nt * 16 + l16;
            const float bv = bias2[n];
            #pragma unroll
            for (int r2 = 0; r2 < 4; ++r2) {
                const int m = mt * 16 + lq * 4 + r2;
                const float v = acc[mt][nt][r2] + bv;
                smem[m * 264 + n] = (f16)(v > 0.f ? v : 0.f);
            }
        }
    BARSYNC();
    // ---- GEMM3: [64,256]@[256,16] via MFMA; waves 0-3 own 16-row slices
    if (w < 4) {
        f32x4 acc3 = (f32x4){0.f, 0.f, 0.f, 0.f};
        const f16* w3row = W3T + (size_t)l16 * 256;
        #pragma unroll
        for (int ks = 0; ks < 8; ++ks) {
            const int koff = ks * 32 + lq * 8;
            const f16x8 af = *(const f16x8*)(&smem[(w * 16 + l16) * 264 + koff]);
            const f16x8 bf = *(const f16x8*)(w3row + koff);
            acc3 = MFMA16(af, bf, acc3);
        }
        const int orow = w * 16 + lq * 4;
        if (!is_speed) {
            if (l16 < 3) {
                const float b3 = bias3[l16];
                #pragma unroll
                for (int r2 = 0; r2 < 4; ++r2) {
                    const int g = rowIdx[orow + r2];
                    if (g >= 0)
                        out[(size_t)g * 3 + l16] = 1.f / (1.f + __expf(-(acc3[r2] + b3)));
                }
            }
        } else {
            if (l16 == 0) {
                const float b3 = bias3[0];
                #pragma unroll
                for (int r2 = 0; r2 < 4; ++r2)
                    out[(size_t)3 * B_ROWS + rowIdx[orow + r2]] = acc3[r2] + b3;
            }
        }
    }
}

extern "C" void kernel_launch(void* const* d_in, const int* in_sizes, int n_in,
                              void* d_out, int out_size, void* d_ws, size_t ws_size,
                              hipStream_t stream) {
    (void)in_sizes; (void)n_in; (void)out_size; (void)ws_size;
    const float* embedding = (const float*)d_in[0];
    const float* speed     = (const float*)d_in[1];
    const int*   command   = (const int*)d_in[2];
    const float* si_W1 = (const float*)d_in[3];
    const float* si_b1 = (const float*)d_in[4];
    const float* si_W2 = (const float*)d_in[5];
    const float* si_b2 = (const float*)d_in[6];
    const float* bW1   = (const float*)d_in[7];
    const float* bb1   = (const float*)d_in[8];
    const float* bW2   = (const float*)d_in[9];
    const float* bb2   = (const float*)d_in[10];
    const float* bW3   = (const float*)d_in[11];
    const float* bb3   = (const float*)d_in[12];
    const float* so_W1 = (const float*)d_in[13];
    const float* so_b1 = (const float*)d_in[14];
    const float* so_W2 = (const float*)d_in[15];
    const float* so_b2 = (const float*)d_in[16];
    const float* so_W3 = (const float*)d_in[17];
    const float* so_b3 = (const float*)d_in[18];
    float* out = (float*)d_out;

    char* ws = (char*)d_ws;
    f16* sF16   = (f16*)(ws + OFF_SF16);
    f16* siW2T  = (f16*)(ws + OFF_SIW2T);
    f16* bW1T   = (f16*)(ws + OFF_BW1T);
    f16* bW2T   = (f16*)(ws + OFF_BW2T);
    f16* soW1T  = (f16*)(ws + OFF_SOW1T);
    f16* soW2T  = (f16*)(ws + OFF_SOW2T);
    f16* bW3T16 = (f16*)(ws + OFF_BW3T16);
    f16* soW3T16= (f16*)(ws + OFF_SOW3T16);
    int* counts = (int*)(ws + OFF_COUNTS);
    int* cursors= (int*)(ws + OFF_CURSORS);
    int* binBase= (int*)(ws + OFF_BINBASE);
    int* tile_cmd = (int*)(ws + OFF_TILECMD);
    int* perm   = (int*)(ws + OFF_PERM);

    prep_kernel<<<1859, dim3(32, 8), 0, stream>>>(
        si_W2, bW1, bW2, so_W1, so_W2, bW3, so_W3,
        siW2T, bW1T, bW2T, soW1T, soW2T, bW3T16, soW3T16,
        counts, cursors, perm);
    speedin_kernel<<<1024, 256, 0, stream>>>(
        speed, si_W1, si_b1, siW2T, si_b2, command, sF16, counts);
    plan_kernel<<<1, 256, 0, stream>>>(counts, binBase, tile_cmd);
    place_kernel<<<256, 256, 0, stream>>>(command, binBase, cursors, perm);
    heads_kernel<<<NT_BRANCH + NT_SPEED, 512, 0, stream>>>(
        embedding, sF16, perm, tile_cmd,
        bW1T, bW2T, bW3T16, bb1, bb2, bb3,
        soW1T, soW2T, soW3T16, so_b1, so_b2, so_b3, out);
}

// Round 4
// 366.029 us; speedup vs baseline: 1.0923x; 1.0923x over previous
//
#include <hip/hip_runtime.h>
#include <cstdint>
#include <cstddef>

typedef _Float16 f16;
typedef f16 f16x8 __attribute__((ext_vector_type(8)));
typedef float f32x4 __attribute__((ext_vector_type(4)));

#define B_ROWS 65536
#define TILE_M 128
#define NT_BRANCH 518    // worst-case 128-row branch tiles: 512 + 6 bins' padding
#define NT_SPEED 512     // 65536/128

// ---------------- ws layout (all offsets 256B-aligned) ----------------
constexpr size_t OFF_SF16   = 0;
constexpr size_t SZ_SF16    = (size_t)B_ROWS * 128 * 2;        // 16,777,216
constexpr size_t OFF_SIW2T  = OFF_SF16 + SZ_SF16;
constexpr size_t SZ_SIW2T   = (size_t)128 * 256 * 2;
constexpr size_t OFF_BW1T   = OFF_SIW2T + SZ_SIW2T;
constexpr size_t SZ_BW1T    = (size_t)6 * 256 * 640 * 2;
constexpr size_t OFF_BW2T   = OFF_BW1T + SZ_BW1T;
constexpr size_t SZ_BW2T    = (size_t)6 * 256 * 256 * 2;
constexpr size_t OFF_SOW1T  = OFF_BW2T + SZ_BW2T;
constexpr size_t SZ_SOW1T   = (size_t)256 * 640 * 2;
constexpr size_t OFF_SOW2T  = OFF_SOW1T + SZ_SOW1T;
constexpr size_t SZ_SOW2T   = (size_t)256 * 256 * 2;
constexpr size_t OFF_BW3T16 = OFF_SOW2T + SZ_SOW2T;
constexpr size_t SZ_BW3T16  = (size_t)6 * 16 * 256 * 2;        // zero-padded cols 3..15
constexpr size_t OFF_SOW3T16= OFF_BW3T16 + SZ_BW3T16;
constexpr size_t SZ_SOW3T16 = (size_t)16 * 256 * 2;
constexpr size_t OFF_COUNTS = OFF_SOW3T16 + SZ_SOW3T16;
constexpr size_t OFF_CURSORS= OFF_COUNTS + 256;
constexpr size_t OFF_BINBASE= OFF_CURSORS + 256;
constexpr size_t OFF_TILECMD= OFF_BINBASE + 256;
constexpr size_t OFF_PERM   = OFF_TILECMD + 4352;
constexpr size_t WS_NEEDED  = OFF_PERM + (size_t)NT_BRANCH * TILE_M * 4;  // ~20.8 MB

#define MFMA16(a, b, c) __builtin_amdgcn_mfma_f32_16x16x32_f16(a, b, c, 0, 0, 0)
// Barrier without the vmcnt(0) drain: LDS ordering only needs lgkmcnt; global
// prefetch loads stay in flight across it.
#define BARSYNC() asm volatile("s_waitcnt lgkmcnt(0)\n\ts_barrier" ::: "memory")

// ---------------- prep: transpose-cast weights + W3T16 + init sort scratch ----------------
__global__ void prep_kernel(const float* __restrict__ siW2,
                            const float* __restrict__ bW1,
                            const float* __restrict__ bW2,
                            const float* __restrict__ soW1,
                            const float* __restrict__ soW2,
                            const float* __restrict__ bW3,
                            const float* __restrict__ soW3,
                            f16* __restrict__ siW2T, f16* __restrict__ bW1T,
                            f16* __restrict__ bW2T, f16* __restrict__ soW1T,
                            f16* __restrict__ soW2T,
                            f16* __restrict__ bW3T16, f16* __restrict__ soW3T16,
                            int* __restrict__ counts, int* __restrict__ cursors,
                            int* __restrict__ perm)
{
    const int bx = blockIdx.x;
    const int tx = threadIdx.x, ty = threadIdx.y;
    const int tid = ty * 32 + tx;
    if (bx >= 1601) {                       // perm init + counter zero
        const int ib = bx - 1601;
        const int idx = ib * 256 + tid;
        if (idx < NT_BRANCH * TILE_M) perm[idx] = -1;
        if (ib == 0 && tid < 6) { counts[tid] = 0; cursors[tid] = 0; }
        return;
    }
    if (bx == 1600) {                       // W3 -> padded-16-col f16, [n][k] layout
        for (int i = tid; i < 6 * 16 * 256; i += 256) {
            const int c = i >> 12, rem = i & 4095, n = rem >> 8, k = rem & 255;
            bW3T16[i] = (n < 3) ? (f16)bW3[((size_t)c * 256 + k) * 3 + n] : (f16)0;
        }
        for (int i = tid; i < 16 * 256; i += 256) {
            const int n = i >> 8, k = i & 255;
            soW3T16[i] = (n == 0) ? (f16)soW3[k] : (f16)0;
        }
        return;
    }
    const float* in; f16* out; int R, C, lb;
    if (bx < 960)       { int m = bx / 160;        lb = bx - m * 160;       in = bW1 + (size_t)m * 640 * 256; out = bW1T + (size_t)m * 640 * 256; R = 640; C = 256; }
    else if (bx < 1344) { int m = (bx - 960) / 64; lb = (bx - 960) - m * 64; in = bW2 + (size_t)m * 256 * 256; out = bW2T + (size_t)m * 256 * 256; R = 256; C = 256; }
    else if (bx < 1504) { lb = bx - 1344; in = soW1; out = soW1T; R = 640; C = 256; }
    else if (bx < 1568) { lb = bx - 1504; in = soW2; out = soW2T; R = 256; C = 256; }
    else                { lb = bx - 1568; in = siW2; out = siW2T; R = 256; C = 128; }
    const int txt = C >> 5;
    const int c0 = (lb % txt) << 5;
    const int r0 = (lb / txt) << 5;
    __shared__ float tile[32][33];
    #pragma unroll
    for (int i = 0; i < 4; ++i)
        tile[tx][ty + 8 * i] = in[(size_t)(r0 + ty + 8 * i) * C + c0 + tx];
    __syncthreads();
    #pragma unroll
    for (int i = 0; i < 4; ++i)
        out[(size_t)(c0 + ty + 8 * i) * R + r0 + tx] = (f16)tile[ty + 8 * i][tx];
}

// ---------------- speed_in MLP (+ fused histogram): sF16 = relu(speed*W1+b1)@W2+b2 ----------------
__global__ __launch_bounds__(256) void speedin_kernel(
    const float* __restrict__ speed,
    const float* __restrict__ siW1, const float* __restrict__ sib1,
    const f16* __restrict__ siW2T, const float* __restrict__ sib2,
    const int* __restrict__ cmd,
    f16* __restrict__ sF16, int* __restrict__ counts)
{
    __shared__ f16 H[64 * 264];
    __shared__ float spd[64];
    __shared__ int h[6];
    const int tid = threadIdx.x;
    const int rb = blockIdx.x * 64;
    if (tid < 6) h[tid] = 0;
    __syncthreads();
    if (tid < 64) {
        spd[tid] = speed[rb + tid];
        atomicAdd(&h[cmd[rb + tid] - 1], 1);
    }
    __syncthreads();
    if (tid < 6 && h[tid] > 0) atomicAdd(&counts[tid], h[tid]);
    {
        const float w1 = siW1[tid], b1v = sib1[tid];
        #pragma unroll 4
        for (int r = 0; r < 64; ++r) {
            float hv = spd[r] * w1 + b1v;
            H[r * 264 + tid] = (f16)(hv > 0.f ? hv : 0.f);
        }
    }
    __syncthreads();
    const int w = tid >> 6, lane = tid & 63, lq = lane >> 4, l16 = lane & 15;
    const int nb = w * 32;
    f32x4 acc[4][2];
    #pragma unroll
    for (int mt = 0; mt < 4; ++mt)
        #pragma unroll
        for (int nt = 0; nt < 2; ++nt)
            acc[mt][nt] = (f32x4){0.f, 0.f, 0.f, 0.f};
    for (int ks = 0; ks < 8; ++ks) {
        const int koff = ks * 32 + lq * 8;
        f16x8 af[4], bf[2];
        #pragma unroll
        for (int mt = 0; mt < 4; ++mt)
            af[mt] = *(const f16x8*)(&H[(mt * 16 + l16) * 264 + koff]);
        #pragma unroll
        for (int nt = 0; nt < 2; ++nt)
            bf[nt] = *(const f16x8*)(siW2T + (size_t)(nb + nt * 16 + l16) * 256 + koff);
        #pragma unroll
        for (int mt = 0; mt < 4; ++mt)
            #pragma unroll
            for (int nt = 0; nt < 2; ++nt)
                acc[mt][nt] = MFMA16(af[mt], bf[nt], acc[mt][nt]);
    }
    #pragma unroll
    for (int mt = 0; mt < 4; ++mt)
        #pragma unroll
        for (int nt = 0; nt < 2; ++nt) {
            const int n = nb + nt * 16 + l16;
            const float bv = sib2[n];
            #pragma unroll
            for (int r2 = 0; r2 < 4; ++r2) {
                const int m = mt * 16 + lq * 4 + r2;
                sF16[(size_t)(rb + m) * 128 + n] = (f16)(acc[mt][nt][r2] + bv);
            }
        }
}

// ---------------- plan: bin bases + tile->command map (128-row tiles) ----------------
__global__ void plan_kernel(const int* __restrict__ counts,
                            int* __restrict__ binBase, int* __restrict__ tile_cmd) {
    __shared__ int tbase[7];
    if (threadIdx.x == 0) {
        int base = 0, tb = 0;
        for (int c = 0; c < 6; ++c) {
            binBase[c] = base;
            tbase[c] = tb;
            const int nt = (counts[c] + TILE_M - 1) >> 7;
            tb += nt;
            base += nt << 7;
        }
        tbase[6] = tb;
    }
    __syncthreads();
    for (int t = threadIdx.x; t < NT_BRANCH; t += 256) {
        int c = -1;
        #pragma unroll
        for (int j = 0; j < 6; ++j)
            if (t >= tbase[j] && t < tbase[j + 1]) c = j;
        tile_cmd[t] = c;
    }
}

__global__ void place_kernel(const int* __restrict__ cmd,
                             const int* __restrict__ binBase,
                             int* __restrict__ cursors, int* __restrict__ perm) {
    __shared__ int lcnt[6], lbase[6];
    const int tid = threadIdx.x;
    if (tid < 6) lcnt[tid] = 0;
    __syncthreads();
    const int i = blockIdx.x * 256 + tid;
    const int c = cmd[i] - 1;
    const int myr = atomicAdd(&lcnt[c], 1);
    __syncthreads();
    if (tid < 6) lbase[tid] = atomicAdd(&cursors[tid], lcnt[tid]);
    __syncthreads();
    perm[binBase[c] + lbase[c] + myr] = i;
}

// Per-thread staging load: 16 cols (2x f16x8) of row `grow`, chunk kc (64 cols).
// kc<8: fp32 embedding cols; kc>=8: f16 sF16 cols.
__device__ __forceinline__ void stage_load2(const float* __restrict__ srcF,
                                            const f16* __restrict__ srcH,
                                            int kc, int p, f16x8* v) {
    if (kc < 8) {
        const float* s = srcF + kc * 64 + p * 16;
        const float4 f0 = ((const float4*)s)[0];
        const float4 f1 = ((const float4*)s)[1];
        const float4 f2 = ((const float4*)s)[2];
        const float4 f3 = ((const float4*)s)[3];
        f16x8 a, b;
        a[0] = (f16)f0.x; a[1] = (f16)f0.y; a[2] = (f16)f0.z; a[3] = (f16)f0.w;
        a[4] = (f16)f1.x; a[5] = (f16)f1.y; a[6] = (f16)f1.z; a[7] = (f16)f1.w;
        b[0] = (f16)f2.x; b[1] = (f16)f2.y; b[2] = (f16)f2.z; b[3] = (f16)f2.w;
        b[4] = (f16)f3.x; b[5] = (f16)f3.y; b[6] = (f16)f3.z; b[7] = (f16)f3.w;
        v[0] = a; v[1] = b;
    } else {
        const f16* s = srcH + (kc - 8) * 64 + p * 16;
        v[0] = ((const f16x8*)s)[0];
        v[1] = ((const f16x8*)s)[1];
    }
}

// ---------------- heads: fused 3-layer MLP, M=128 tile for 2x arithmetic intensity ----------------
// 512 threads = 8 waves; wave-tile 128x32 (acc 8x2); M=128 rows per block.
// Weight traffic per output row HALVES vs M=64 (W1T+W2T ~450KB read once per
// 128 rows instead of per 64). A dbuf 2x[128][72] aliases h buffer [128][264].
__global__ __launch_bounds__(512, 3) void heads_kernel(
    const float* __restrict__ emb,        // [B,512] fp32
    const f16* __restrict__ sF16,         // [B,128]
    const int* __restrict__ perm, const int* __restrict__ tile_cmd,
    const f16* __restrict__ bW1T, const f16* __restrict__ bW2T,
    const f16* __restrict__ bW3T16,
    const float* __restrict__ bb1, const float* __restrict__ bb2,
    const float* __restrict__ bb3,
    const f16* __restrict__ soW1T, const f16* __restrict__ soW2T,
    const f16* __restrict__ soW3T16,
    const float* __restrict__ sob1, const float* __restrict__ sob2,
    const float* __restrict__ sob3,
    float* __restrict__ out)
{
    __shared__ f16 smem[33792];           // h [128][264]; A dbuf 2x[128][72] aliases base
    __shared__ int rowIdx[TILE_M];
    const int bx = blockIdx.x;
    const int tid = threadIdx.x;
    const bool is_speed = (bx >= NT_BRANCH);
    const f16 *W1T, *W2T, *W3T;
    const float *bias1, *bias2, *bias3;
    if (is_speed) {
        const int t = bx - NT_BRANCH;
        if (tid < TILE_M) rowIdx[tid] = t * TILE_M + tid;
        W1T = soW1T; W2T = soW2T; W3T = soW3T16;
        bias1 = sob1; bias2 = sob2; bias3 = sob3;
    } else {
        const int c = tile_cmd[bx];
        if (c < 0) return;               // block-uniform
        if (tid < TILE_M) rowIdx[tid] = perm[bx * TILE_M + tid];
        W1T = bW1T + (size_t)c * 256 * 640;
        W2T = bW2T + (size_t)c * 256 * 256;
        W3T = bW3T16 + (size_t)c * 16 * 256;
        bias1 = bb1 + c * 256; bias2 = bb2 + c * 256; bias3 = bb3 + c * 3;
    }
    __syncthreads();

    // staging role: thread covers row r (0..127), 16-col group p (0..3)
    const int r = tid >> 2, p = tid & 3;
    int growS = rowIdx[r]; if (growS < 0) growS = 0;
    const float* srcF = emb + (size_t)growS * 512;
    const f16*   srcH = sF16 + (size_t)growS * 128;
    const int pOff = r * 72 + p * 16;

    const int w = tid >> 6, lane = tid & 63, lq = lane >> 4, l16 = lane & 15;
    const int nb = w * 32;               // wave's N slice of 256
    const f16* brow0 = W1T + (size_t)(nb + l16) * 640;
    const f16* brow1 = W1T + (size_t)(nb + 16 + l16) * 640;

    f32x4 acc[8][2];
    #pragma unroll
    for (int mt = 0; mt < 8; ++mt)
        #pragma unroll
        for (int nt = 0; nt < 2; ++nt)
            acc[mt][nt] = (f32x4){0.f, 0.f, 0.f, 0.f};

    // ---- GEMM1: K=640 in 10 chunks of 64; A ring depth-3; B one chunk ahead
    f16x8 sreg[3][2];
    #pragma unroll
    for (int j = 0; j < 3; ++j)
        stage_load2(srcF, srcH, j, p, sreg[j]);
    f16x8 Bb[2][2];                       // current chunk [ks][nt]
    #pragma unroll
    for (int ks = 0; ks < 2; ++ks) {
        Bb[ks][0] = *(const f16x8*)(brow0 + ks * 32 + lq * 8);
        Bb[ks][1] = *(const f16x8*)(brow1 + ks * 32 + lq * 8);
    }
    *(f16x8*)(smem + pOff) = sreg[0][0];  // buf0 <- chunk0
    *(f16x8*)(smem + pOff + 8) = sreg[0][1];
    BARSYNC();

    #pragma unroll
    for (int kc = 0; kc < 10; ++kc) {
        const f16* cur = smem + (kc & 1) * 9216;
        if (kc < 9) {                      // publish chunk kc+1 into other buffer
            f16* dst = smem + ((kc + 1) & 1) * 9216 + pOff;
            *(f16x8*)(dst)     = sreg[(kc + 1) % 3][0];
            *(f16x8*)(dst + 8) = sreg[(kc + 1) % 3][1];
        }
        if (kc < 7)                        // refill freed slot with chunk kc+3
            stage_load2(srcF, srcH, kc + 3, p, sreg[kc % 3]);
        f16x8 Bn[2][2];
        if (kc < 9) {                      // next-chunk B (L2-resident weights)
            #pragma unroll
            for (int ks = 0; ks < 2; ++ks) {
                Bn[ks][0] = *(const f16x8*)(brow0 + (kc + 1) * 64 + ks * 32 + lq * 8);
                Bn[ks][1] = *(const f16x8*)(brow1 + (kc + 1) * 64 + ks * 32 + lq * 8);
            }
        }
        #pragma unroll
        for (int ks = 0; ks < 2; ++ks)
            #pragma unroll
            for (int mh = 0; mh < 2; ++mh) {
                f16x8 a[4];
                #pragma unroll
                for (int mt = 0; mt < 4; ++mt)
                    a[mt] = *(const f16x8*)(cur + ((mh * 4 + mt) * 16 + l16) * 72 + ks * 32 + lq * 8);
                #pragma unroll
                for (int mt = 0; mt < 4; ++mt) {
                    acc[mh * 4 + mt][0] = MFMA16(a[mt], Bb[ks][0], acc[mh * 4 + mt][0]);
                    acc[mh * 4 + mt][1] = MFMA16(a[mt], Bb[ks][1], acc[mh * 4 + mt][1]);
                }
            }
        if (kc < 9) {
            #pragma unroll
            for (int ks = 0; ks < 2; ++ks)
                #pragma unroll
                for (int nt = 0; nt < 2; ++nt)
                    Bb[ks][nt] = Bn[ks][nt];
        }
        BARSYNC();
    }

    // prefetch GEMM2 B (ks=0) behind the epilogue
    const f16* brow2[2];
    #pragma unroll
    for (int nt = 0; nt < 2; ++nt)
        brow2[nt] = W2T + (size_t)(nb + nt * 16 + l16) * 256;
    f16x8 Bd[2][2];
    #pragma unroll
    for (int nt = 0; nt < 2; ++nt)
        Bd[0][nt] = *(const f16x8*)(brow2[nt] + lq * 8);

    // h1 = relu(acc + b1) -> smem [128][264]
    #pragma unroll
    for (int mt = 0; mt < 8; ++mt)
        #pragma unroll
        for (int nt = 0; nt < 2; ++nt) {
            const int n = nb + nt * 16 + l16;
            const float bv = bias1[n];
            #pragma unroll
            for (int r2 = 0; r2 < 4; ++r2) {
                const int m = mt * 16 + lq * 4 + r2;
                const float v = acc[mt][nt][r2] + bv;
                smem[m * 264 + n] = (f16)(v > 0.f ? v : 0.f);
            }
            acc[mt][nt] = (f32x4){0.f, 0.f, 0.f, 0.f};
        }
    BARSYNC();

    // ---- GEMM2: K=256, A=h1 (LDS), B dbuf one ks ahead
    #pragma unroll
    for (int ks = 0; ks < 8; ++ks) {
        if (ks < 7) {
            #pragma unroll
            for (int nt = 0; nt < 2; ++nt)
                Bd[(ks + 1) & 1][nt] = *(const f16x8*)(brow2[nt] + (ks + 1) * 32 + lq * 8);
        }
        #pragma unroll
        for (int mh = 0; mh < 2; ++mh) {
            f16x8 a[4];
            #pragma unroll
            for (int mt = 0; mt < 4; ++mt)
                a[mt] = *(const f16x8*)(&smem[((mh * 4 + mt) * 16 + l16) * 264 + ks * 32 + lq * 8]);
            #pragma unroll
            for (int mt = 0; mt < 4; ++mt) {
                acc[mh * 4 + mt][0] = MFMA16(a[mt], Bd[ks & 1][0], acc[mh * 4 + mt][0]);
                acc[mh * 4 + mt][1] = MFMA16(a[mt], Bd[ks & 1][1], acc[mh * 4 + mt][1]);
            }
        }
    }
    BARSYNC();
    // h2 = relu(acc + b2) -> smem
    #pragma unroll
    for (int mt = 0; mt < 8; ++mt)
        #pragma unroll
        for (int nt = 0; nt < 2; ++nt) {
            const int n = nb + nt * 16 + l16;
            const float bv = bias2[n];
            #pragma unroll
            for (int r2 = 0; r2 < 4; ++r2) {
                const int m = mt * 16 + lq * 4 + r2;
                const float v = acc[mt][nt][r2] + bv;
                smem[m * 264 + n] = (f16)(v > 0.f ? v : 0.f);
            }
        }
    BARSYNC();
    // ---- GEMM3: [128,256]@[256,16] via MFMA; all 8 waves own 16-row slices
    {
        f32x4 acc3 = (f32x4){0.f, 0.f, 0.f, 0.f};
        const f16* w3row = W3T + (size_t)l16 * 256;
        #pragma unroll
        for (int ks = 0; ks < 8; ++ks) {
            const int koff = ks * 32 + lq * 8;
            const f16x8 af = *(const f16x8*)(&smem[(w * 16 + l16) * 264 + koff]);
            const f16x8 bf = *(const f16x8*)(w3row + koff);
            acc3 = MFMA16(af, bf, acc3);
        }
        const int orow = w * 16 + lq * 4;
        if (!is_speed) {
            if (l16 < 3) {
                const float b3 = bias3[l16];
                #pragma unroll
                for (int r2 = 0; r2 < 4; ++r2) {
                    const int g = rowIdx[orow + r2];
                    if (g >= 0)
                        out[(size_t)g * 3 + l16] = 1.f / (1.f + __expf(-(acc3[r2] + b3)));
                }
            }
        } else {
            if (l16 == 0) {
                const float b3 = bias3[0];
                #pragma unroll
                for (int r2 = 0; r2 < 4; ++r2) {
                    const int g = rowIdx[orow + r2];
                    if (g >= 0)
                        out[(size_t)3 * B_ROWS + g] = acc3[r2] + b3;
                }
            }
        }
    }
}

extern "C" void kernel_launch(void* const* d_in, const int* in_sizes, int n_in,
                              void* d_out, int out_size, void* d_ws, size_t ws_size,
                              hipStream_t stream) {
    (void)in_sizes; (void)n_in; (void)out_size; (void)ws_size;
    const float* embedding = (const float*)d_in[0];
    const float* speed     = (const float*)d_in[1];
    const int*   command   = (const int*)d_in[2];
    const float* si_W1 = (const float*)d_in[3];
    const float* si_b1 = (const float*)d_in[4];
    const float* si_W2 = (const float*)d_in[5];
    const float* si_b2 = (const float*)d_in[6];
    const float* bW1   = (const float*)d_in[7];
    const float* bb1   = (const float*)d_in[8];
    const float* bW2   = (const float*)d_in[9];
    const float* bb2   = (const float*)d_in[10];
    const float* bW3   = (const float*)d_in[11];
    const float* bb3   = (const float*)d_in[12];
    const float* so_W1 = (const float*)d_in[13];
    const float* so_b1 = (const float*)d_in[14];
    const float* so_W2 = (const float*)d_in[15];
    const float* so_b2 = (const float*)d_in[16];
    const float* so_W3 = (const float*)d_in[17];
    const float* so_b3 = (const float*)d_in[18];
    float* out = (float*)d_out;

    char* ws = (char*)d_ws;
    f16* sF16   = (f16*)(ws + OFF_SF16);
    f16* siW2T  = (f16*)(ws + OFF_SIW2T);
    f16* bW1T   = (f16*)(ws + OFF_BW1T);
    f16* bW2T   = (f16*)(ws + OFF_BW2T);
    f16* soW1T  = (f16*)(ws + OFF_SOW1T);
    f16* soW2T  = (f16*)(ws + OFF_SOW2T);
    f16* bW3T16 = (f16*)(ws + OFF_BW3T16);
    f16* soW3T16= (f16*)(ws + OFF_SOW3T16);
    int* counts = (int*)(ws + OFF_COUNTS);
    int* cursors= (int*)(ws + OFF_CURSORS);
    int* binBase= (int*)(ws + OFF_BINBASE);
    int* tile_cmd = (int*)(ws + OFF_TILECMD);
    int* perm   = (int*)(ws + OFF_PERM);

    prep_kernel<<<1860, dim3(32, 8), 0, stream>>>(
        si_W2, bW1, bW2, so_W1, so_W2, bW3, so_W3,
        siW2T, bW1T, bW2T, soW1T, soW2T, bW3T16, soW3T16,
        counts, cursors, perm);
    speedin_kernel<<<1024, 256, 0, stream>>>(
        speed, si_W1, si_b1, siW2T, si_b2, command, sF16, counts);
    plan_kernel<<<1, 256, 0, stream>>>(counts, binBase, tile_cmd);
    place_kernel<<<256, 256, 0, stream>>>(command, binBase, cursors, perm);
    heads_kernel<<<NT_BRANCH + NT_SPEED, 512, 0, stream>>>(
        embedding, sF16, perm, tile_cmd,
        bW1T, bW2T, bW3T16, bb1, bb2, bb3,
        soW1T, soW2T, soW3T16, so_b1, so_b2, so_b3, out);
}